// Round 1
// baseline (300.573 us; speedup 1.0000x reference)
//
#include <hip/hip_runtime.h>

#define NB 48
#define NT 5000
#define NF 161
#define NROWS (NB * NT)        // 240000
#define MAGN  (NROWS * NF)     // 38640000

// Kernel A: per-row weighted power + sqrt.  One wave (64 lanes) per row.
// sp = (2*sum(all m^2) - m0^2 - mN^2)/320  computed as weighted sum.
__global__ __launch_bounds__(256) void x_kernel(const float* __restrict__ mag,
                                                float* __restrict__ gout) {
    const int wave = threadIdx.x >> 6;
    const int lane = threadIdx.x & 63;
    const int row  = blockIdx.x * 4 + wave;
    if (row >= NROWS) return;
    const float* rp = mag + (size_t)row * NF;
    float sum = 0.f;
#pragma unroll
    for (int k0 = 0; k0 < NF; k0 += 64) {
        int k = k0 + lane;
        if (k < NF) {
            float v = rp[k];
            float w = (k == 0 || k == NF - 1) ? 1.f : 2.f;
            sum += w * v * v;
        }
    }
#pragma unroll
    for (int off = 32; off > 0; off >>= 1)
        sum += __shfl_down(sum, off, 64);
    if (lane == 0)
        gout[row] = sqrtf(sum / 320.f);
}

// Kernel B: in-place EMA scan over T per batch.  One block per batch.
// Affine-composite parallel scan: segment == map g -> A*g + B.
__global__ __launch_bounds__(256) void scan_kernel(float* __restrict__ gbuf) {
    __shared__ float sx[NT];          // 20000 B
    __shared__ float sA[256];
    __shared__ float sB[256];
    const int b   = blockIdx.x;
    const int tid = threadIdx.x;
    float* gp = gbuf + (size_t)b * NT;

    for (int t = tid; t < NT; t += 256) sx[t] = gp[t];
    __syncthreads();

    const int LEN   = 20;                       // ceil((NT-1)/256)
    const int start = 1 + tid * LEN;
    const int end   = min(NT, start + LEN);

    float A = 1.f, Bc = 0.f;
    for (int t = start; t < end; ++t) {
        A  *= 0.9f;
        Bc  = 0.9f * Bc + 0.1f * sx[t];
    }
    sA[tid] = A; sB[tid] = Bc;
    __syncthreads();

    // Hillis-Steele inclusive scan of affine maps
    for (int off = 1; off < 256; off <<= 1) {
        float a = sA[tid], bb = sB[tid];
        float ap = 1.f, bp = 0.f;
        if (tid >= off) { ap = sA[tid - off]; bp = sB[tid - off]; }
        __syncthreads();
        sA[tid] = a * ap;
        sB[tid] = a * bp + bb;
        __syncthreads();
    }

    // exclusive prefix of this thread = inclusive of tid-1; seed g[0] = x[0]
    float Ap = 1.f, Bp = 0.f;
    if (tid > 0) { Ap = sA[tid - 1]; Bp = sB[tid - 1]; }
    float g = Ap * sx[0] + Bp;                 // g at t = start-1

    if (tid == 0) gp[0] = sx[0];
    for (int t = start; t < end; ++t) {
        g = 0.9f * g + 0.1f * sx[t];
        gp[t] = g;
    }
}

// Kernel C: new_mag = mag * rcp(gain[row] + 0.001), float4-vectorized.
__global__ __launch_bounds__(256) void div_kernel(const float* __restrict__ mag,
                                                  const float* __restrict__ gain,
                                                  float* __restrict__ out) {
    const unsigned n4 = MAGN / 4u;            // 9660000
    const unsigned i4 = blockIdx.x * 256u + threadIdx.x;
    if (i4 >= n4) return;

    float4 m = ((const float4*)mag)[i4];
    const unsigned base = i4 * 4u;
    const unsigned row0 = base / NF;          // magic-mul div by 161
    const unsigned row3 = (base + 3u) / NF;   // at most one row boundary in 4 elems
    const float ga = __builtin_amdgcn_rcpf(gain[row0] + 0.001f);
    const float gb = __builtin_amdgcn_rcpf(gain[row3] + 0.001f);
    const unsigned lim = (row0 + 1u) * NF;    // first index of next row

    float4 o;
    o.x = m.x * ga;
    o.y = m.y * ((base + 1u < lim) ? ga : gb);
    o.z = m.z * ((base + 2u < lim) ? ga : gb);
    o.w = m.w * gb;
    ((float4*)out)[i4] = o;
}

extern "C" void kernel_launch(void* const* d_in, const int* in_sizes, int n_in,
                              void* d_out, int out_size, void* d_ws, size_t ws_size,
                              hipStream_t stream) {
    const float* mag = (const float*)d_in[0];
    float* out  = (float*)d_out;
    float* gout = out + (size_t)MAGN;          // slice_gain region [B*T]

    x_kernel<<<NROWS / 4, 256, 0, stream>>>(mag, gout);
    scan_kernel<<<NB, 256, 0, stream>>>(gout);
    div_kernel<<<(MAGN / 4 + 255) / 256, 256, 0, stream>>>(mag, gout, out);
}

// Round 2
// 288.940 us; speedup vs baseline: 1.0403x; 1.0403x over previous
//
#include <hip/hip_runtime.h>

#define NB 48
#define NT 5000
#define NF 161
#define NROWS (NB * NT)        // 240000
#define MAGN  (NROWS * NF)     // 38640000

// Kernel A: per-row weighted power + sqrt.
// Block = 256 threads = 16 rows = 2576 floats = 644 float4 (fully dense
// dwordx4 global loads) staged through LDS; 4 waves reduce 4 rows each.
__global__ __launch_bounds__(256) void x_kernel(const float* __restrict__ mag,
                                                float* __restrict__ gout) {
    __shared__ float sx[16 * NF];            // 2576 floats, 10304 B
    const int tid  = threadIdx.x;
    const int wave = tid >> 6;
    const int lane = tid & 63;
    const size_t blk_base = (size_t)blockIdx.x * (16 * NF);

    // dense float4 staging: 644 float4 per block
    const float4* gp4 = (const float4*)(mag + blk_base);
    float4* sp4 = (float4*)sx;
#pragma unroll
    for (int j = 0; j < 3; ++j) {
        int i4 = tid + 256 * j;
        if (i4 < (16 * NF) / 4) sp4[i4] = gp4[i4];
    }
    __syncthreads();

    // wave w reduces rows w*4 .. w*4+3
#pragma unroll
    for (int i = 0; i < 4; ++i) {
        const int r = wave * 4 + i;
        const float* rp = sx + r * NF;
        float sum = 0.f;
#pragma unroll
        for (int k0 = 0; k0 < NF; k0 += 64) {
            int k = k0 + lane;
            if (k < NF) {
                float v = rp[k];
                float w = (k == 0 || k == NF - 1) ? 1.f : 2.f;
                sum += w * v * v;
            }
        }
#pragma unroll
        for (int off = 32; off > 0; off >>= 1)
            sum += __shfl_down(sum, off, 64);
        if (lane == 0)
            gout[blockIdx.x * 16 + r] = sqrtf(sum / 320.f);
    }
}

// Kernel B: in-place EMA scan over T per batch.  One block per batch.
// Affine-composite parallel scan: segment == map g -> A*g + B.
__global__ __launch_bounds__(256) void scan_kernel(float* __restrict__ gbuf) {
    __shared__ float sx[NT];          // 20000 B
    __shared__ float sA[256];
    __shared__ float sB[256];
    const int b   = blockIdx.x;
    const int tid = threadIdx.x;
    float* gp = gbuf + (size_t)b * NT;

    for (int t = tid; t < NT; t += 256) sx[t] = gp[t];
    __syncthreads();

    const int LEN   = 20;                       // ceil((NT-1)/256)
    const int start = 1 + tid * LEN;
    const int end   = min(NT, start + LEN);

    float A = 1.f, Bc = 0.f;
    for (int t = start; t < end; ++t) {
        A  *= 0.9f;
        Bc  = 0.9f * Bc + 0.1f * sx[t];
    }
    sA[tid] = A; sB[tid] = Bc;
    __syncthreads();

    // Hillis-Steele inclusive scan of affine maps
    for (int off = 1; off < 256; off <<= 1) {
        float a = sA[tid], bb = sB[tid];
        float ap = 1.f, bp = 0.f;
        if (tid >= off) { ap = sA[tid - off]; bp = sB[tid - off]; }
        __syncthreads();
        sA[tid] = a * ap;
        sB[tid] = a * bp + bb;
        __syncthreads();
    }

    // exclusive prefix of this thread = inclusive of tid-1; seed g[0] = x[0]
    float Ap = 1.f, Bp = 0.f;
    if (tid > 0) { Ap = sA[tid - 1]; Bp = sB[tid - 1]; }
    float g = Ap * sx[0] + Bp;                 // g at t = start-1

    if (tid == 0) gp[0] = sx[0];
    for (int t = start; t < end; ++t) {
        g = 0.9f * g + 0.1f * sx[t];
        gp[t] = g;
    }
}

// Kernel C: new_mag = mag * rcp(gain[row] + 0.001), float4-vectorized.
__global__ __launch_bounds__(256) void div_kernel(const float* __restrict__ mag,
                                                  const float* __restrict__ gain,
                                                  float* __restrict__ out) {
    const unsigned n4 = MAGN / 4u;            // 9660000
    const unsigned i4 = blockIdx.x * 256u + threadIdx.x;
    if (i4 >= n4) return;

    float4 m = ((const float4*)mag)[i4];
    const unsigned base = i4 * 4u;
    const unsigned row0 = base / NF;          // magic-mul div by 161
    const unsigned row3 = (base + 3u) / NF;   // at most one row boundary in 4 elems
    const float ga = __builtin_amdgcn_rcpf(gain[row0] + 0.001f);
    const float gb = __builtin_amdgcn_rcpf(gain[row3] + 0.001f);
    const unsigned lim = (row0 + 1u) * NF;    // first index of next row

    float4 o;
    o.x = m.x * ga;
    o.y = m.y * ((base + 1u < lim) ? ga : gb);
    o.z = m.z * ((base + 2u < lim) ? ga : gb);
    o.w = m.w * gb;
    ((float4*)out)[i4] = o;
}

extern "C" void kernel_launch(void* const* d_in, const int* in_sizes, int n_in,
                              void* d_out, int out_size, void* d_ws, size_t ws_size,
                              hipStream_t stream) {
    const float* mag = (const float*)d_in[0];
    float* out  = (float*)d_out;
    float* gout = out + (size_t)MAGN;          // slice_gain region [B*T]

    x_kernel<<<NROWS / 16, 256, 0, stream>>>(mag, gout);
    scan_kernel<<<NB, 256, 0, stream>>>(gout);
    div_kernel<<<(MAGN / 4 + 255) / 256, 256, 0, stream>>>(mag, gout, out);
}